// Round 2
// baseline (421.027 us; speedup 1.0000x reference)
//
#include <hip/hip_runtime.h>
#include <cstdint>
#include <cstddef>

// ================= VQ layer: N=32768 pts, D=256, K=8192 codes ==================
// prepE (LDS-transpose) -> e2z (e2 + zero scratch) -> screen (f16 MFMA, 64 rows/
// wave, exact top-2 per col-quarter) -> merge (combine quarters, flag) ->
// rescan (candidates for flagged) -> exact (fp64) -> gather (+loss)
#define NPTS    32768
#define DDIM    256
#define KCOD    8192
#define NELEM   8388608           // NPTS*DDIM
#define BIAS    4096.0f
#define WINDOW  12.0f             // covers 2*delta'(f16) + packed-storage slop(4)
#define FLAGCAP 16384
#define CANDCAP 16

typedef _Float16 half8 __attribute__((ext_vector_type(8)));
typedef float    f32x4 __attribute__((ext_vector_type(4)));

__device__ __forceinline__ unsigned umin_(unsigned a, unsigned b){ return a<b?a:b; }
__device__ __forceinline__ unsigned umax_(unsigned a, unsigned b){ return a>b?a:b; }

// --------------------------------------------------------------- prepE
// Per block: 64 cols x 256 d. Coalesced E reads -> LDS tile -> Et rows (fp32,
// [k][d]) + EhP (f16(16*E), MFMA B-frag order, 32-col chunks).
// EhP elem idx = chunk*8192 + (st*2+nb)*512 + (q*16+n16)*8 + j
//   where col = chunk*32 + nb*16 + n16, d = st*32 + q*8 + j.
__global__ void k_prepE(const float* __restrict__ E, _Float16* __restrict__ EhP,
                        float* __restrict__ Et) {
  __shared__ float T[64][65];
  const int tid = threadIdx.x;
  const int k0 = blockIdx.x * 64;        // 128 blocks
  const int c0 = blockIdx.x * 2;         // 2 chunks of 32 cols per block
  for (int dstep = 0; dstep < 4; ++dstep) {
    __syncthreads();
    { // load 64 d x 64 k, coalesced (wave reads 64 consecutive k)
      const int kl = tid & 63, wq = tid >> 6;
      #pragma unroll
      for (int rr = 0; rr < 16; ++rr) {
        int dl = rr*4 + wq;
        T[dl][kl] = E[(size_t)(dstep*64 + dl)*KCOD + k0 + kl];
      }
    }
    __syncthreads();
    { // Et rows: [k][d] contiguous
      const int kl = tid >> 2, fq = tid & 3;
      #pragma unroll
      for (int iter = 0; iter < 4; ++iter) {
        int db = iter*16 + fq*4;
        float4 v = make_float4(T[db][kl], T[db+1][kl], T[db+2][kl], T[db+3][kl]);
        *(float4*)(Et + (size_t)(k0+kl)*DDIM + dstep*64 + db) = v;
      }
    }
    { // EhP frag-order halves (512 groups of 8 this dstep)
      #pragma unroll
      for (int gi = 0; gi < 2; ++gi) {
        int g = gi*256 + tid;
        int n16 = g & 15, q = (g>>4)&3, nb = (g>>6)&1, stp = (g>>7)&1, ch = (g>>8)&1;
        int st = dstep*2 + stp;
        int kl = ch*32 + nb*16 + n16;
        int dl = stp*32 + q*8;
        half8 h;
        #pragma unroll
        for (int j = 0; j < 8; ++j) h[j] = (_Float16)(16.0f * T[dl + j][kl]);
        *(half8*)(EhP + (size_t)(c0+ch)*8192 + (st*2+nb)*512 + (q*16+n16)*8) = h;
      }
    }
  }
}

// ------------------------------ e2p[k] = 256*||E_k||^2 + BIAS, + zero scratch
__global__ void k_e2z(const float* __restrict__ E, float* __restrict__ e2p,
                      int* __restrict__ ccounts, int* __restrict__ flagcount,
                      float* __restrict__ out_loss) {
  const int k = blockIdx.x*256 + threadIdx.x;    // 32 blocks -> 8192 threads
  float s = 0.0f;
  #pragma unroll 4
  for (int d = 0; d < DDIM; ++d) { float v = E[(size_t)d*KCOD + k]; s = fmaf(v, v, s); }
  e2p[k] = 256.0f*s + BIAS;
  ccounts[k] = 0; ccounts[k + 8192] = 0;
  if (k == 0) { *flagcount = 0; *out_loss = 0.0f; }
}

// --------------------------------------------------------- P1: f16 MFMA screen
// 512 blocks = 128 rowgroups x 4 col-quarters. Block = 4 waves x 64 rows = 256
// rows; chunk = 32 cols (16 KB LDS). Exact in-lane top-2 (value+idx), merged
// across 16 lp-lanes; per-quarter results to m1q (packed val|col) / m2q.
__launch_bounds__(256, 2)
__global__ void k_screen(const float* __restrict__ X, const _Float16* __restrict__ EhP,
                         const float* __restrict__ e2p, unsigned* __restrict__ m1q,
                         float* __restrict__ m2q)
{
  __shared__ __align__(16) _Float16 Bsh[8192];   // 16 KB
  const int tid = threadIdx.x;
  const int lane = tid & 63, wid = tid >> 6;
  const int q = lane >> 4, lp = lane & 15;
  const int rg = blockIdx.x >> 2, qtr = blockIdx.x & 3;
  const int rowbase = rg*256 + wid*64;

  // A fragments: 64 rows/wave, register-resident (128 VGPRs)
  half8 af[4][8];
  #pragma unroll
  for (int mb = 0; mb < 4; ++mb) {
    const float* xr = X + (size_t)(rowbase + mb*16 + lp)*DDIM;
    #pragma unroll
    for (int st = 0; st < 8; ++st) {
      const float* p = xr + st*32 + q*8;
      float4 v0 = *(const float4*)p;
      float4 v1 = *(const float4*)(p + 4);
      half8 h;
      h[0]=(_Float16)(16.f*v0.x); h[1]=(_Float16)(16.f*v0.y);
      h[2]=(_Float16)(16.f*v0.z); h[3]=(_Float16)(16.f*v0.w);
      h[4]=(_Float16)(16.f*v1.x); h[5]=(_Float16)(16.f*v1.y);
      h[6]=(_Float16)(16.f*v1.z); h[7]=(_Float16)(16.f*v1.w);
      af[mb][st] = h;
    }
  }

  float m1f[4][4], m2f[4][4]; int i1[4][4];
  #pragma unroll
  for (int mb=0;mb<4;++mb)
    #pragma unroll
    for (int r=0;r<4;++r) { m1f[mb][r]=3.0e38f; m2f[mb][r]=3.0e38f; i1[mb][r]=0; }

  for (int cc = 0; cc < 64; ++cc) {
    const int c = qtr*64 + cc;
    __syncthreads();
    { // stage 16 KB chunk (frag order already baked in)
      const uint4* src = (const uint4*)(EhP + (size_t)c*8192) + tid;
      uint4* dst = (uint4*)Bsh + tid;
      #pragma unroll
      for (int r = 0; r < 4; ++r) dst[r*256] = src[r*256];
    }
    __syncthreads();

    f32x4 acc[4][2];
    #pragma unroll
    for (int mb=0;mb<4;++mb)
      #pragma unroll
      for (int nb=0;nb<2;++nb) { f32x4 z = {0.f,0.f,0.f,0.f}; acc[mb][nb] = z; }

    #pragma unroll
    for (int st = 0; st < 8; ++st) {
      half8 bf[2];
      #pragma unroll
      for (int nb = 0; nb < 2; ++nb)
        bf[nb] = *(const half8*)(Bsh + ((st*2 + nb)*512 + lane*8));
      #pragma unroll
      for (int nb = 0; nb < 2; ++nb)
        #pragma unroll
        for (int mb = 0; mb < 4; ++mb)
          acc[mb][nb] = __builtin_amdgcn_mfma_f32_16x16x32_f16(af[mb][st], bf[nb], acc[mb][nb], 0, 0, 0);
    }

    #pragma unroll
    for (int nb = 0; nb < 2; ++nb) {
      const int col = c*32 + nb*16 + lp;
      const float e2v = e2p[col];
      #pragma unroll
      for (int mb = 0; mb < 4; ++mb)
        #pragma unroll
        for (int r = 0; r < 4; ++r) {
          float s = fmaf(-2.0f, acc[mb][nb][r], e2v);
          // exact top-2: med3 for 2nd-best (uses old m1), cndmask for best+idx
          m2f[mb][r] = __builtin_amdgcn_fmed3f(m1f[mb][r], m2f[mb][r], s);
          bool lt = s < m1f[mb][r];
          m1f[mb][r] = lt ? s : m1f[mb][r];
          i1[mb][r]  = lt ? col : i1[mb][r];
        }
    }
  }

  // merge across the 16 lp-lanes of each quad (waves own disjoint rows)
  #pragma unroll
  for (int off = 1; off <= 8; off <<= 1) {
    #pragma unroll
    for (int mb=0;mb<4;++mb)
      #pragma unroll
      for (int r=0;r<4;++r) {
        float o1 = __shfl_xor(m1f[mb][r], off);
        int   oi = __shfl_xor(i1[mb][r],  off);
        float o2 = __shfl_xor(m2f[mb][r], off);
        float hi = fmaxf(m1f[mb][r], o1);
        m2f[mb][r] = fminf(fminf(m2f[mb][r], o2), hi);
        if (o1 < m1f[mb][r]) { m1f[mb][r] = o1; i1[mb][r] = oi; }
      }
  }
  if (lp == 0) {
    #pragma unroll
    for (int mb=0;mb<4;++mb)
      #pragma unroll
      for (int r=0;r<4;++r) {
        int row = rowbase + mb*16 + q*4 + r;
        unsigned u = (__float_as_uint(m1f[mb][r]) & 0xFFFFE000u) | (unsigned)i1[mb][r];
        m1q[qtr*NPTS + row] = u;
        m2q[qtr*NPTS + row] = m2f[mb][r];
      }
  }
}

// ------------------------------------- merge 4 quarters, write idx/m1s, flag
__global__ void k_merge(const unsigned* __restrict__ m1q, const float* __restrict__ m2q,
                        int* __restrict__ idx, float* __restrict__ m1s,
                        int* __restrict__ flaglist, int* __restrict__ flagcount)
{
  const int row = blockIdx.x*256 + threadIdx.x;   // 128 blocks
  unsigned u0 = m1q[row], u1 = m1q[NPTS + row], u2 = m1q[2*NPTS + row], u3 = m1q[3*NPTS + row];
  float    w0 = m2q[row], w1 = m2q[NPTS + row], w2 = m2q[2*NPTS + row], w3 = m2q[3*NPTS + row];
  unsigned a = umin_(u0,u1), b = umax_(u0,u1), cx = umin_(u2,u3), d = umax_(u2,u3);
  unsigned m1g = umin_(a, cx);
  unsigned sec = umin_(umax_(a, cx), umin_(b, d));
  float m1f = __uint_as_float(m1g & 0xFFFFE000u);
  float secf = __uint_as_float(sec & 0xFFFFE000u);
  float m2g = fminf(fminf(fminf(w0,w1), fminf(w2,w3)), secf);
  idx[row] = (int)(m1g & 0x1FFFu);
  m1s[row] = m1f;
  if (m2g - m1f < WINDOW) {
    int p = atomicAdd(flagcount, 1);
    if (p < FLAGCAP) flaglist[p] = row;
  }
}

// -------------------------------- P2: rescan flagged rows, collect candidates
// grid 128 = 8 batch-slots x 16 K-slices (16 chunks each). Batch = 256 rows.
__launch_bounds__(256, 2)
__global__ void k_rescan(const float* __restrict__ X, const _Float16* __restrict__ EhP,
                         const float* __restrict__ e2p, const float* __restrict__ m1s,
                         const int* __restrict__ flaglist, const int* __restrict__ flagcount,
                         int* __restrict__ ccounts, int* __restrict__ candbuf)
{
  __shared__ __align__(16) _Float16 Bsh[8192];
  const int tid = threadIdx.x, lane = tid & 63, wid = tid >> 6;
  const int q = lane >> 4, lp = lane & 15;
  const int slice = blockIdx.x & 15, bslot = blockIdx.x >> 4;
  int cnt = *flagcount; if (cnt > FLAGCAP) cnt = FLAGCAP;

  for (int batch = bslot; batch*256 < cnt; batch += 8) {
    const int base = batch*256 + wid*64;
    int ga[4];
    #pragma unroll
    for (int mb=0;mb<4;++mb) {
      int fi = base + mb*16 + lp;
      ga[mb] = (fi < cnt) ? flaglist[fi] : 0;
    }
    float thr[4][4]; int fis[4][4];
    #pragma unroll
    for (int mb=0;mb<4;++mb)
      #pragma unroll
      for (int r=0;r<4;++r) {
        int fi = base + mb*16 + q*4 + r;
        fis[mb][r] = fi;
        if (fi < cnt) thr[mb][r] = m1s[flaglist[fi]] + WINDOW;
        else          thr[mb][r] = -3.0e38f;
      }
    half8 af[4][8];
    #pragma unroll
    for (int mb = 0; mb < 4; ++mb) {
      const float* xr = X + (size_t)ga[mb]*DDIM;
      #pragma unroll
      for (int st = 0; st < 8; ++st) {
        const float* p = xr + st*32 + q*8;
        float4 v0 = *(const float4*)p;
        float4 v1 = *(const float4*)(p + 4);
        half8 h;
        h[0]=(_Float16)(16.f*v0.x); h[1]=(_Float16)(16.f*v0.y);
        h[2]=(_Float16)(16.f*v0.z); h[3]=(_Float16)(16.f*v0.w);
        h[4]=(_Float16)(16.f*v1.x); h[5]=(_Float16)(16.f*v1.y);
        h[6]=(_Float16)(16.f*v1.z); h[7]=(_Float16)(16.f*v1.w);
        af[mb][st] = h;
      }
    }
    for (int j = 0; j < 16; ++j) {
      const int c = slice*16 + j;
      __syncthreads();
      { const uint4* src = (const uint4*)(EhP + (size_t)c*8192) + tid;
        uint4* dst = (uint4*)Bsh + tid;
        #pragma unroll
        for (int r = 0; r < 4; ++r) dst[r*256] = src[r*256];
      }
      __syncthreads();
      f32x4 acc[4][2];
      #pragma unroll
      for (int mb=0;mb<4;++mb)
        #pragma unroll
        for (int nb=0;nb<2;++nb) { f32x4 z = {0.f,0.f,0.f,0.f}; acc[mb][nb] = z; }
      #pragma unroll
      for (int st = 0; st < 8; ++st) {
        half8 bf[2];
        #pragma unroll
        for (int nb = 0; nb < 2; ++nb)
          bf[nb] = *(const half8*)(Bsh + ((st*2 + nb)*512 + lane*8));
        #pragma unroll
        for (int nb = 0; nb < 2; ++nb)
          #pragma unroll
          for (int mb = 0; mb < 4; ++mb)
            acc[mb][nb] = __builtin_amdgcn_mfma_f32_16x16x32_f16(af[mb][st], bf[nb], acc[mb][nb], 0, 0, 0);
      }
      #pragma unroll
      for (int nb = 0; nb < 2; ++nb) {
        const int col = c*32 + nb*16 + lp;
        const float e2v = e2p[col];
        #pragma unroll
        for (int mb = 0; mb < 4; ++mb)
          #pragma unroll
          for (int r = 0; r < 4; ++r) {
            float s = fmaf(-2.0f, acc[mb][nb][r], e2v);
            if (s < thr[mb][r]) {
              int fi = fis[mb][r];
              int slot = atomicAdd(&ccounts[fi], 1);
              if (slot < CANDCAP) candbuf[fi*CANDCAP + slot] = col;
            }
          }
      }
    }
  }
}

// -------------------------------------- P3: exact fp64 argmin over candidates
__global__ void k_exact(const float* __restrict__ X, const float* __restrict__ Et,
                        const int* __restrict__ flaglist, const int* __restrict__ flagcount,
                        const int* __restrict__ ccounts, const int* __restrict__ candbuf,
                        int* __restrict__ idx)
{
  int cnt = *flagcount; if (cnt > FLAGCAP) cnt = FLAGCAP;
  const int lane = threadIdx.x & 63;
  const int w = blockIdx.x*4 + (threadIdx.x >> 6);
  for (int i = w; i < cnt; i += 256) {
    const int g = flaglist[i];
    const int cc = ccounts[i];
    double best = 1.0e300; int bestk = 0x7FFFFFFF;
    if (cc <= CANDCAP) {
      float4 xv = *(const float4*)(X + (size_t)g*DDIM + lane*4);
      for (int c = 0; c < cc; ++c) {
        int k = candbuf[i*CANDCAP + c];
        float4 ev = *(const float4*)(Et + (size_t)k*DDIM + lane*4);
        double d0 = (double)xv.x - (double)ev.x, d1 = (double)xv.y - (double)ev.y;
        double d2 = (double)xv.z - (double)ev.z, d3 = (double)xv.w - (double)ev.w;
        double s = d0*d0 + d1*d1 + d2*d2 + d3*d3;
        #pragma unroll
        for (int off = 1; off < 64; off <<= 1) s += __shfl_xor(s, off);
        if (s < best || (s == best && k < bestk)) { best = s; bestk = k; }
      }
    } else {  // candbuf overflow: full exact scan (statistically ~never)
      double bb = 1.0e300; int bk = 0x7FFFFFFF;
      for (int k = lane; k < KCOD; k += 64) {
        double s = 0.0;
        for (int d = 0; d < DDIM; ++d) {
          double df = (double)X[(size_t)g*DDIM + d] - (double)Et[(size_t)k*DDIM + d];
          s += df*df;
        }
        if (s < bb || (s == bb && k < bk)) { bb = s; bk = k; }
      }
      #pragma unroll
      for (int off = 1; off < 64; off <<= 1) {
        double ob = __shfl_xor(bb, off); int ok = __shfl_xor(bk, off);
        if (ob < bb || (ob == bb && ok < bk)) { bb = ob; bk = ok; }
      }
      best = bb; bestk = bk;
    }
    if (lane == 0 && bestk != 0x7FFFFFFF) idx[g] = bestk;
  }
}

// -------------------------------------------------- P4: gather output + loss
__global__ void k_gather(const float* __restrict__ X, const float* __restrict__ Et,
                         const int* __restrict__ idx, float* __restrict__ out)
{
  const int lane = threadIdx.x & 63, wid = threadIdx.x >> 6;
  float lsum = 0.0f;
  for (int i = 0; i < 16; ++i) {
    int n = blockIdx.x*64 + i*4 + wid;
    int k = idx[n];
    float4 xv = *(const float4*)(X  + (size_t)n*DDIM + lane*4);
    float4 ev = *(const float4*)(Et + (size_t)k*DDIM + lane*4);
    *(float4*)(out + (size_t)n*DDIM + lane*4) = ev;   // ST fwd value == quantized
    float d0 = ev.x-xv.x, d1 = ev.y-xv.y, d2 = ev.z-xv.z, d3 = ev.w-xv.w;
    lsum += d0*d0 + d1*d1 + d2*d2 + d3*d3;
  }
  #pragma unroll
  for (int off = 1; off < 64; off <<= 1) lsum += __shfl_xor(lsum, off);
  if (lane == 0) atomicAdd(out + (size_t)NELEM, lsum * (1.25f/8388608.0f));
}

// ================================ launch ======================================
extern "C" void kernel_launch(void* const* d_in, const int* in_sizes, int n_in,
                              void* d_out, int out_size, void* d_ws, size_t ws_size,
                              hipStream_t stream)
{
  const float* X = (const float*)d_in[0];   // [32768][256]
  const float* E = (const float*)d_in[1];   // [256][8192]
  float* out = (float*)d_out;               // [8388608 quantized][1 loss]
  char* ws = (char*)d_ws;

  float*     Et        = (float*)(ws);                               // 8 MB
  _Float16*  EhP       = (_Float16*)(ws + 8388608);                  // 4 MB
  float*     e2p       = (float*)(ws + 12582912);                    // 32 KB
  unsigned*  m1q       = (unsigned*)(ws + 12615680);                 // 512 KB
  float*     m2q       = (float*)(ws + 13139968);                    // 512 KB
  float*     m1s       = (float*)(ws + 13664256);                    // 128 KB
  int*       idx       = (int*)(ws + 13795328);                      // 128 KB
  int*       flaglist  = (int*)(ws + 13926400);                      // 64 KB
  int*       ccounts   = (int*)(ws + 13991936);                      // 64 KB
  int*       candbuf   = (int*)(ws + 14057472);                      // 1 MB
  int*       flagcount = (int*)(ws + 15106048);                      // 4 B
  if (ws_size < (size_t)15106052) return;

  dim3 B(256);
  k_prepE <<<dim3(128), B, 0, stream>>>(E, EhP, Et);
  k_e2z   <<<dim3(32),  B, 0, stream>>>(E, e2p, ccounts, flagcount, out + NELEM);
  k_screen<<<dim3(512), B, 0, stream>>>(X, EhP, e2p, m1q, m2q);
  k_merge <<<dim3(128), B, 0, stream>>>(m1q, m2q, idx, m1s, flaglist, flagcount);
  k_rescan<<<dim3(128), B, 0, stream>>>(X, EhP, e2p, m1s, flaglist, flagcount, ccounts, candbuf);
  k_exact <<<dim3(64),  B, 0, stream>>>(X, Et, flaglist, flagcount, ccounts, candbuf, idx);
  k_gather<<<dim3(512), B, 0, stream>>>(X, Et, idx, out);
}

// Round 3
// 370.949 us; speedup vs baseline: 1.1350x; 1.1350x over previous
//
#include <hip/hip_runtime.h>
#include <cstdint>
#include <cstddef>

// ================= VQ layer: N=32768 pts, D=256, K=8192 codes ==================
// prepE (LDS-transpose, 512 blocks) -> e2z (from Et, 2048 blocks, + zero) ->
// screen (f16 MFMA, NO LDS: B-frags direct from global/L1, zero barriers) ->
// merge -> rescan (LDS-free) -> exact (fp64) -> gather (+loss)
#define NPTS    32768
#define DDIM    256
#define KCOD    8192
#define NELEM   8388608           // NPTS*DDIM
#define BIAS    4096.0f
#define WINDOW  12.0f
#define FLAGCAP 16384
#define CANDCAP 16

typedef _Float16 half8 __attribute__((ext_vector_type(8)));
typedef float    f32x4 __attribute__((ext_vector_type(4)));

__device__ __forceinline__ unsigned umin_(unsigned a, unsigned b){ return a<b?a:b; }
__device__ __forceinline__ unsigned umax_(unsigned a, unsigned b){ return a>b?a:b; }

// --------------------------------------------------------------- prepE
// 512 blocks = 128 colgroups x 4 dsteps; per block: 64 cols x 64 d tile.
// EhP elem idx = chunk*8192 + (st*2+nb)*512 + (q*16+n16)*8 + j
//   where col = chunk*32 + nb*16 + n16, d = st*32 + q*8 + j.
__global__ void k_prepE(const float* __restrict__ E, _Float16* __restrict__ EhP,
                        float* __restrict__ Et) {
  __shared__ float T[64][65];
  const int tid = threadIdx.x;
  const int cg = blockIdx.x & 127, dstep = blockIdx.x >> 7;
  const int k0 = cg*64, c0 = cg*2;
  { // load 64 d x 64 k, coalesced within 256B rows
    const int kl = tid & 63, wq = tid >> 6;
    #pragma unroll
    for (int rr = 0; rr < 16; ++rr) {
      int dl = rr*4 + wq;
      T[dl][kl] = E[(size_t)(dstep*64 + dl)*KCOD + k0 + kl];
    }
  }
  __syncthreads();
  { // Et rows: [k][d] contiguous
    const int kk = tid >> 2, fq = tid & 3;
    #pragma unroll
    for (int iter = 0; iter < 4; ++iter) {
      int db = iter*16 + fq*4;
      float4 v = make_float4(T[db][kk], T[db+1][kk], T[db+2][kk], T[db+3][kk]);
      *(float4*)(Et + (size_t)(k0+kk)*DDIM + dstep*64 + db) = v;
    }
  }
  { // EhP frag-order (512 groups of 8 this dstep)
    #pragma unroll
    for (int gi = 0; gi < 2; ++gi) {
      int g = gi*256 + tid;
      int n16 = g & 15, q = (g>>4)&3, nb = (g>>6)&1, stp = (g>>7)&1, ch = (g>>8)&1;
      int st = dstep*2 + stp;
      int kl2 = ch*32 + nb*16 + n16;
      int dl = stp*32 + q*8;
      half8 h;
      #pragma unroll
      for (int j = 0; j < 8; ++j) h[j] = (_Float16)(16.0f * T[dl + j][kl2]);
      *(half8*)(EhP + (size_t)(c0+ch)*8192 + (st*2+nb)*512 + (q*16+n16)*8) = h;
    }
  }
}

// --------------- e2p[k] = 256*||E_k||^2 + BIAS (from Et, coalesced) + zeroing
__global__ void k_e2z(const float* __restrict__ Et, float* __restrict__ e2p,
                      int* __restrict__ ccounts, int* __restrict__ flagcount,
                      float* __restrict__ out_loss) {
  const int lane = threadIdx.x & 63, wid = threadIdx.x >> 6;
  const int k = blockIdx.x*4 + wid;                     // 2048 blocks
  float4 v = *((const float4*)(Et + (size_t)k*DDIM) + lane);
  float s = v.x*v.x + v.y*v.y + v.z*v.z + v.w*v.w;
  #pragma unroll
  for (int off = 1; off < 64; off <<= 1) s += __shfl_xor(s, off);
  if (lane == 0) e2p[k] = 256.0f*s + BIAS;
  int t = blockIdx.x*256 + threadIdx.x;
  if (t < FLAGCAP) ccounts[t] = 0;
  if (t == 0) { *flagcount = 0; *out_loss = 0.0f; }
}

// --------------------------------------------------------- P1: f16 MFMA screen
// 512 blocks = 4 col-quarters x 128 rowgroups (qtr = blockIdx>>7 so co-resident
// blocks share a quarter -> L1 reuse). Block = 4 waves x 64 rows = 256 rows.
// NO LDS, NO barriers: B-frags loaded directly from global (16B/lane coalesced,
// chunk is 16KB -> L1-resident, broadcast across waves/blocks).
__launch_bounds__(256, 2)
__global__ void k_screen(const float* __restrict__ X, const _Float16* __restrict__ EhP,
                         const float* __restrict__ e2p, unsigned* __restrict__ m1q,
                         float* __restrict__ m2q)
{
  const int tid = threadIdx.x;
  const int lane = tid & 63;
  const int wid = tid >> 6;
  const int q = lane >> 4, lp = lane & 15;
  const int rg = blockIdx.x & 127, qtr = blockIdx.x >> 7;
  const int rowbase = rg*256 + wid*64;

  // A fragments: 64 rows/wave, register-resident (128 VGPRs)
  half8 af[4][8];
  #pragma unroll
  for (int mb = 0; mb < 4; ++mb) {
    const float* xr = X + (size_t)(rowbase + mb*16 + lp)*DDIM;
    #pragma unroll
    for (int st = 0; st < 8; ++st) {
      const float* p = xr + st*32 + q*8;
      float4 v0 = *(const float4*)p;
      float4 v1 = *(const float4*)(p + 4);
      half8 h;
      h[0]=(_Float16)(16.f*v0.x); h[1]=(_Float16)(16.f*v0.y);
      h[2]=(_Float16)(16.f*v0.z); h[3]=(_Float16)(16.f*v0.w);
      h[4]=(_Float16)(16.f*v1.x); h[5]=(_Float16)(16.f*v1.y);
      h[6]=(_Float16)(16.f*v1.z); h[7]=(_Float16)(16.f*v1.w);
      af[mb][st] = h;
    }
  }

  float m1f[4][4], m2f[4][4]; int i1[4][4];
  #pragma unroll
  for (int mb=0;mb<4;++mb)
    #pragma unroll
    for (int r=0;r<4;++r) { m1f[mb][r]=3.0e38f; m2f[mb][r]=3.0e38f; i1[mb][r]=0; }

  for (int cc = 0; cc < 64; ++cc) {
    const int c = qtr*64 + cc;
    const _Float16* Bp = EhP + (size_t)c*8192 + lane*8;

    f32x4 acc[4][2];
    #pragma unroll
    for (int mb=0;mb<4;++mb)
      #pragma unroll
      for (int nb=0;nb<2;++nb) { f32x4 z = {0.f,0.f,0.f,0.f}; acc[mb][nb] = z; }

    #pragma unroll
    for (int st = 0; st < 8; ++st) {
      half8 bf[2];
      bf[0] = *(const half8*)(Bp + (st*2+0)*512);
      bf[1] = *(const half8*)(Bp + (st*2+1)*512);
      #pragma unroll
      for (int nb = 0; nb < 2; ++nb)
        #pragma unroll
        for (int mb = 0; mb < 4; ++mb)
          acc[mb][nb] = __builtin_amdgcn_mfma_f32_16x16x32_f16(af[mb][st], bf[nb], acc[mb][nb], 0, 0, 0);
    }

    #pragma unroll
    for (int nb = 0; nb < 2; ++nb) {
      const int col = c*32 + nb*16 + lp;
      const float e2v = e2p[col];
      #pragma unroll
      for (int mb = 0; mb < 4; ++mb)
        #pragma unroll
        for (int r = 0; r < 4; ++r) {
          float s = fmaf(-2.0f, acc[mb][nb][r], e2v);
          m2f[mb][r] = __builtin_amdgcn_fmed3f(m1f[mb][r], m2f[mb][r], s);
          bool lt = s < m1f[mb][r];
          m1f[mb][r] = lt ? s : m1f[mb][r];
          i1[mb][r]  = lt ? col : i1[mb][r];
        }
    }
  }

  // merge across the 16 lp-lanes of each quad (waves own disjoint rows)
  #pragma unroll
  for (int off = 1; off <= 8; off <<= 1) {
    #pragma unroll
    for (int mb=0;mb<4;++mb)
      #pragma unroll
      for (int r=0;r<4;++r) {
        float o1 = __shfl_xor(m1f[mb][r], off);
        int   oi = __shfl_xor(i1[mb][r],  off);
        float o2 = __shfl_xor(m2f[mb][r], off);
        float hi = fmaxf(m1f[mb][r], o1);
        m2f[mb][r] = fminf(fminf(m2f[mb][r], o2), hi);
        if (o1 < m1f[mb][r]) { m1f[mb][r] = o1; i1[mb][r] = oi; }
      }
  }
  if (lp == 0) {
    #pragma unroll
    for (int mb=0;mb<4;++mb)
      #pragma unroll
      for (int r=0;r<4;++r) {
        int row = rowbase + mb*16 + q*4 + r;
        unsigned u = (__float_as_uint(m1f[mb][r]) & 0xFFFFE000u) | (unsigned)i1[mb][r];
        m1q[qtr*NPTS + row] = u;
        m2q[qtr*NPTS + row] = m2f[mb][r];
      }
  }
}

// ------------------------------------- merge 4 quarters, write idx/m1s, flag
__global__ void k_merge(const unsigned* __restrict__ m1q, const float* __restrict__ m2q,
                        int* __restrict__ idx, float* __restrict__ m1s,
                        int* __restrict__ flaglist, int* __restrict__ flagcount)
{
  const int row = blockIdx.x*256 + threadIdx.x;   // 128 blocks
  unsigned u0 = m1q[row], u1 = m1q[NPTS + row], u2 = m1q[2*NPTS + row], u3 = m1q[3*NPTS + row];
  float    w0 = m2q[row], w1 = m2q[NPTS + row], w2 = m2q[2*NPTS + row], w3 = m2q[3*NPTS + row];
  unsigned a = umin_(u0,u1), b = umax_(u0,u1), cx = umin_(u2,u3), d = umax_(u2,u3);
  unsigned m1g = umin_(a, cx);
  unsigned sec = umin_(umax_(a, cx), umin_(b, d));
  float m1f = __uint_as_float(m1g & 0xFFFFE000u);
  float secf = __uint_as_float(sec & 0xFFFFE000u);
  float m2g = fminf(fminf(fminf(w0,w1), fminf(w2,w3)), secf);
  idx[row] = (int)(m1g & 0x1FFFu);
  m1s[row] = m1f;
  if (m2g - m1f < WINDOW) {
    int p = atomicAdd(flagcount, 1);
    if (p < FLAGCAP) flaglist[p] = row;
  }
}

// -------------------------------- P2: rescan flagged rows, collect candidates
// grid 512 = 16 batch-slots x 32 K-slices (8 chunks each). LDS-free like screen.
__launch_bounds__(256, 2)
__global__ void k_rescan(const float* __restrict__ X, const _Float16* __restrict__ EhP,
                         const float* __restrict__ e2p, const float* __restrict__ m1s,
                         const int* __restrict__ flaglist, const int* __restrict__ flagcount,
                         int* __restrict__ ccounts, int* __restrict__ candbuf)
{
  const int tid = threadIdx.x, lane = tid & 63, wid = tid >> 6;
  const int q = lane >> 4, lp = lane & 15;
  const int slice = blockIdx.x & 31, bslot = blockIdx.x >> 5;
  int cnt = *flagcount; if (cnt > FLAGCAP) cnt = FLAGCAP;

  for (int batch = bslot; batch*256 < cnt; batch += 16) {
    const int base = batch*256 + wid*64;
    int ga[4];
    #pragma unroll
    for (int mb=0;mb<4;++mb) {
      int fi = base + mb*16 + lp;
      ga[mb] = (fi < cnt) ? flaglist[fi] : 0;
    }
    float thr[4][4]; int fis[4][4];
    #pragma unroll
    for (int mb=0;mb<4;++mb)
      #pragma unroll
      for (int r=0;r<4;++r) {
        int fi = base + mb*16 + q*4 + r;
        fis[mb][r] = fi;
        if (fi < cnt) thr[mb][r] = m1s[flaglist[fi]] + WINDOW;
        else          thr[mb][r] = -3.0e38f;
      }
    half8 af[4][8];
    #pragma unroll
    for (int mb = 0; mb < 4; ++mb) {
      const float* xr = X + (size_t)ga[mb]*DDIM;
      #pragma unroll
      for (int st = 0; st < 8; ++st) {
        const float* p = xr + st*32 + q*8;
        float4 v0 = *(const float4*)p;
        float4 v1 = *(const float4*)(p + 4);
        half8 h;
        h[0]=(_Float16)(16.f*v0.x); h[1]=(_Float16)(16.f*v0.y);
        h[2]=(_Float16)(16.f*v0.z); h[3]=(_Float16)(16.f*v0.w);
        h[4]=(_Float16)(16.f*v1.x); h[5]=(_Float16)(16.f*v1.y);
        h[6]=(_Float16)(16.f*v1.z); h[7]=(_Float16)(16.f*v1.w);
        af[mb][st] = h;
      }
    }
    for (int j = 0; j < 8; ++j) {
      const int c = slice*8 + j;
      const _Float16* Bp = EhP + (size_t)c*8192 + lane*8;
      f32x4 acc[4][2];
      #pragma unroll
      for (int mb=0;mb<4;++mb)
        #pragma unroll
        for (int nb=0;nb<2;++nb) { f32x4 z = {0.f,0.f,0.f,0.f}; acc[mb][nb] = z; }
      #pragma unroll
      for (int st = 0; st < 8; ++st) {
        half8 bf[2];
        bf[0] = *(const half8*)(Bp + (st*2+0)*512);
        bf[1] = *(const half8*)(Bp + (st*2+1)*512);
        #pragma unroll
        for (int nb = 0; nb < 2; ++nb)
          #pragma unroll
          for (int mb = 0; mb < 4; ++mb)
            acc[mb][nb] = __builtin_amdgcn_mfma_f32_16x16x32_f16(af[mb][st], bf[nb], acc[mb][nb], 0, 0, 0);
      }
      #pragma unroll
      for (int nb = 0; nb < 2; ++nb) {
        const int col = c*32 + nb*16 + lp;
        const float e2v = e2p[col];
        #pragma unroll
        for (int mb = 0; mb < 4; ++mb)
          #pragma unroll
          for (int r = 0; r < 4; ++r) {
            float s = fmaf(-2.0f, acc[mb][nb][r], e2v);
            if (s < thr[mb][r]) {
              int fi = fis[mb][r];
              int slot = atomicAdd(&ccounts[fi], 1);
              if (slot < CANDCAP) candbuf[fi*CANDCAP + slot] = col;
            }
          }
      }
    }
  }
}

// -------------------------------------- P3: exact fp64 argmin over candidates
__global__ void k_exact(const float* __restrict__ X, const float* __restrict__ Et,
                        const int* __restrict__ flaglist, const int* __restrict__ flagcount,
                        const int* __restrict__ ccounts, const int* __restrict__ candbuf,
                        int* __restrict__ idx)
{
  int cnt = *flagcount; if (cnt > FLAGCAP) cnt = FLAGCAP;
  const int lane = threadIdx.x & 63;
  const int w = blockIdx.x*4 + (threadIdx.x >> 6);      // 256 blocks -> 1024 waves
  for (int i = w; i < cnt; i += 1024) {
    const int g = flaglist[i];
    const int cc = ccounts[i];
    double best = 1.0e300; int bestk = 0x7FFFFFFF;
    if (cc <= CANDCAP) {
      float4 xv = *(const float4*)(X + (size_t)g*DDIM + lane*4);
      for (int c = 0; c < cc; ++c) {
        int k = candbuf[i*CANDCAP + c];
        float4 ev = *(const float4*)(Et + (size_t)k*DDIM + lane*4);
        double d0 = (double)xv.x - (double)ev.x, d1 = (double)xv.y - (double)ev.y;
        double d2 = (double)xv.z - (double)ev.z, d3 = (double)xv.w - (double)ev.w;
        double s = d0*d0 + d1*d1 + d2*d2 + d3*d3;
        #pragma unroll
        for (int off = 1; off < 64; off <<= 1) s += __shfl_xor(s, off);
        if (s < best || (s == best && k < bestk)) { best = s; bestk = k; }
      }
    } else {  // candbuf overflow: full exact scan (statistically ~never)
      double bb = 1.0e300; int bk = 0x7FFFFFFF;
      for (int k = lane; k < KCOD; k += 64) {
        double s = 0.0;
        for (int d = 0; d < DDIM; ++d) {
          double df = (double)X[(size_t)g*DDIM + d] - (double)Et[(size_t)k*DDIM + d];
          s += df*df;
        }
        if (s < bb || (s == bb && k < bk)) { bb = s; bk = k; }
      }
      #pragma unroll
      for (int off = 1; off < 64; off <<= 1) {
        double ob = __shfl_xor(bb, off); int ok = __shfl_xor(bk, off);
        if (ob < bb || (ob == bb && ok < bk)) { bb = ob; bk = ok; }
      }
      best = bb; bestk = bk;
    }
    if (lane == 0 && bestk != 0x7FFFFFFF) idx[g] = bestk;
  }
}

// -------------------------------------------------- P4: gather output + loss
__global__ void k_gather(const float* __restrict__ X, const float* __restrict__ Et,
                         const int* __restrict__ idx, float* __restrict__ out)
{
  const int lane = threadIdx.x & 63, wid = threadIdx.x >> 6;
  float lsum = 0.0f;
  for (int i = 0; i < 16; ++i) {
    int n = blockIdx.x*64 + i*4 + wid;
    int k = idx[n];
    float4 xv = *(const float4*)(X  + (size_t)n*DDIM + lane*4);
    float4 ev = *(const float4*)(Et + (size_t)k*DDIM + lane*4);
    *(float4*)(out + (size_t)n*DDIM + lane*4) = ev;   // ST fwd value == quantized
    float d0 = ev.x-xv.x, d1 = ev.y-xv.y, d2 = ev.z-xv.z, d3 = ev.w-xv.w;
    lsum += d0*d0 + d1*d1 + d2*d2 + d3*d3;
  }
  #pragma unroll
  for (int off = 1; off < 64; off <<= 1) lsum += __shfl_xor(lsum, off);
  if (lane == 0) atomicAdd(out + (size_t)NELEM, lsum * (1.25f/8388608.0f));
}

// ================================ launch ======================================
extern "C" void kernel_launch(void* const* d_in, const int* in_sizes, int n_in,
                              void* d_out, int out_size, void* d_ws, size_t ws_size,
                              hipStream_t stream)
{
  const float* X = (const float*)d_in[0];   // [32768][256]
  const float* E = (const float*)d_in[1];   // [256][8192]
  float* out = (float*)d_out;               // [8388608 quantized][1 loss]
  char* ws = (char*)d_ws;

  float*     Et        = (float*)(ws);                               // 8 MB
  _Float16*  EhP       = (_Float16*)(ws + 8388608);                  // 4 MB
  float*     e2p       = (float*)(ws + 12582912);                    // 32 KB
  unsigned*  m1q       = (unsigned*)(ws + 12615680);                 // 512 KB
  float*     m2q       = (float*)(ws + 13139968);                    // 512 KB
  float*     m1s       = (float*)(ws + 13664256);                    // 128 KB
  int*       idx       = (int*)(ws + 13795328);                      // 128 KB
  int*       flaglist  = (int*)(ws + 13926400);                      // 64 KB
  int*       ccounts   = (int*)(ws + 13991936);                      // 64 KB
  int*       candbuf   = (int*)(ws + 14057472);                      // 1 MB
  int*       flagcount = (int*)(ws + 15106048);                      // 4 B
  if (ws_size < (size_t)15106052) return;

  dim3 B(256);
  k_prepE <<<dim3(512),  B, 0, stream>>>(E, EhP, Et);
  k_e2z   <<<dim3(2048), B, 0, stream>>>(Et, e2p, ccounts, flagcount, out + NELEM);
  k_screen<<<dim3(512),  B, 0, stream>>>(X, EhP, e2p, m1q, m2q);
  k_merge <<<dim3(128),  B, 0, stream>>>(m1q, m2q, idx, m1s, flaglist, flagcount);
  k_rescan<<<dim3(512),  B, 0, stream>>>(X, EhP, e2p, m1s, flaglist, flagcount, ccounts, candbuf);
  k_exact <<<dim3(256),  B, 0, stream>>>(X, Et, flaglist, flagcount, ccounts, candbuf, idx);
  k_gather<<<dim3(512),  B, 0, stream>>>(X, Et, idx, out);
}

// Round 4
// 300.075 us; speedup vs baseline: 1.4031x; 1.2362x over previous
//
#include <hip/hip_runtime.h>
#include <cstdint>
#include <cstddef>

// ================= VQ layer: N=32768 pts, D=256, K=8192 codes ==================
// prepE (LDS-transpose, 512 blocks) -> e2z (from Et, 2048 blocks, + zero) ->
// screen (f16 MFMA, double-buffered LDS via async global_load_lds width=16,
// ONE barrier/chunk) -> merge -> rescan (same dbuf) -> exact (fp64) -> gather
#define NPTS    32768
#define DDIM    256
#define KCOD    8192
#define NELEM   8388608           // NPTS*DDIM
#define BIAS    4096.0f
#define WINDOW  8.0f              // ~11 sigma of f16-score error model
#define FLAGCAP 16384
#define CANDCAP 16

typedef _Float16 half8 __attribute__((ext_vector_type(8)));
typedef float    f32x4 __attribute__((ext_vector_type(4)));

__device__ __forceinline__ unsigned umin_(unsigned a, unsigned b){ return a<b?a:b; }
__device__ __forceinline__ unsigned umax_(unsigned a, unsigned b){ return a>b?a:b; }

// async global->LDS, 16B per lane; lds dest must be linear in lane order
__device__ __forceinline__ void gl_lds16(const void* g, void* l) {
  __builtin_amdgcn_global_load_lds(
      (const __attribute__((address_space(1))) unsigned int*)g,
      (__attribute__((address_space(3))) unsigned int*)l, 16, 0, 0);
}

// --------------------------------------------------------------- prepE
// 512 blocks = 128 colgroups x 4 dsteps; per block: 64 cols x 64 d tile.
// EhP elem idx = chunk*8192 + (st*2+nb)*512 + (q*16+n16)*8 + j
//   where col = chunk*32 + nb*16 + n16, d = st*32 + q*8 + j.
__global__ void k_prepE(const float* __restrict__ E, _Float16* __restrict__ EhP,
                        float* __restrict__ Et) {
  __shared__ float T[64][65];
  const int tid = threadIdx.x;
  const int cg = blockIdx.x & 127, dstep = blockIdx.x >> 7;
  const int k0 = cg*64, c0 = cg*2;
  { // load 64 d x 64 k, coalesced within 256B rows
    const int kl = tid & 63, wq = tid >> 6;
    #pragma unroll
    for (int rr = 0; rr < 16; ++rr) {
      int dl = rr*4 + wq;
      T[dl][kl] = E[(size_t)(dstep*64 + dl)*KCOD + k0 + kl];
    }
  }
  __syncthreads();
  { // Et rows: [k][d] contiguous
    const int kk = tid >> 2, fq = tid & 3;
    #pragma unroll
    for (int iter = 0; iter < 4; ++iter) {
      int db = iter*16 + fq*4;
      float4 v = make_float4(T[db][kk], T[db+1][kk], T[db+2][kk], T[db+3][kk]);
      *(float4*)(Et + (size_t)(k0+kk)*DDIM + dstep*64 + db) = v;
    }
  }
  { // EhP frag-order (512 groups of 8 this dstep)
    #pragma unroll
    for (int gi = 0; gi < 2; ++gi) {
      int g = gi*256 + tid;
      int n16 = g & 15, q = (g>>4)&3, nb = (g>>6)&1, stp = (g>>7)&1, ch = (g>>8)&1;
      int st = dstep*2 + stp;
      int kl2 = ch*32 + nb*16 + n16;
      int dl = stp*32 + q*8;
      half8 h;
      #pragma unroll
      for (int j = 0; j < 8; ++j) h[j] = (_Float16)(16.0f * T[dl + j][kl2]);
      *(half8*)(EhP + (size_t)(c0+ch)*8192 + (st*2+nb)*512 + (q*16+n16)*8) = h;
    }
  }
}

// --------------- e2p[k] = 256*||E_k||^2 + BIAS (from Et, coalesced) + zeroing
__global__ void k_e2z(const float* __restrict__ Et, float* __restrict__ e2p,
                      int* __restrict__ ccounts, int* __restrict__ flagcount,
                      float* __restrict__ out_loss) {
  const int lane = threadIdx.x & 63, wid = threadIdx.x >> 6;
  const int k = blockIdx.x*4 + wid;                     // 2048 blocks
  float4 v = *((const float4*)(Et + (size_t)k*DDIM) + lane);
  float s = v.x*v.x + v.y*v.y + v.z*v.z + v.w*v.w;
  #pragma unroll
  for (int off = 1; off < 64; off <<= 1) s += __shfl_xor(s, off);
  if (lane == 0) e2p[k] = 256.0f*s + BIAS;
  int t = blockIdx.x*256 + threadIdx.x;
  if (t < FLAGCAP) ccounts[t] = 0;
  if (t == 0) { *flagcount = 0; *out_loss = 0.0f; }
}

// --------------------------------------------------------- P1: f16 MFMA screen
// 512 blocks = 4 col-quarters (major) x 128 rowgroups. Block = 4 waves x 64
// rows = 256 rows; chunk = 32 cols (16 KB). Double-buffered LDS, async
// global_load_lds staging issued right after the single per-chunk barrier.
__launch_bounds__(256, 2)
__global__ void k_screen(const float* __restrict__ X, const _Float16* __restrict__ EhP,
                         const float* __restrict__ e2p, unsigned* __restrict__ m1q,
                         float* __restrict__ m2q)
{
  __shared__ __align__(16) _Float16 Bsh[2][8192];   // 2 x 16 KB
  const int tid = threadIdx.x;
  const int lane = tid & 63, wid = tid >> 6;
  const int q = lane >> 4, lp = lane & 15;
  const int rg = blockIdx.x & 127, qtr = blockIdx.x >> 7;
  const int rowbase = rg*256 + wid*64;
  const int stag = wid*1024 + lane*16;              // per-lane byte offset

  { // issue chunk 0 staging (overlaps the A-fragment build below)
    const char* g = (const char*)(EhP + (size_t)(qtr*64)*8192);
    #pragma unroll
    for (int r = 0; r < 4; ++r)
      gl_lds16(g + r*4096 + stag, (char*)&Bsh[0][0] + r*4096 + stag);
  }

  // A fragments: 64 rows/wave, register-resident
  half8 af[4][8];
  #pragma unroll
  for (int mb = 0; mb < 4; ++mb) {
    const float* xr = X + (size_t)(rowbase + mb*16 + lp)*DDIM;
    #pragma unroll
    for (int st = 0; st < 8; ++st) {
      const float* p = xr + st*32 + q*8;
      float4 v0 = *(const float4*)p;
      float4 v1 = *(const float4*)(p + 4);
      half8 h;
      h[0]=(_Float16)(16.f*v0.x); h[1]=(_Float16)(16.f*v0.y);
      h[2]=(_Float16)(16.f*v0.z); h[3]=(_Float16)(16.f*v0.w);
      h[4]=(_Float16)(16.f*v1.x); h[5]=(_Float16)(16.f*v1.y);
      h[6]=(_Float16)(16.f*v1.z); h[7]=(_Float16)(16.f*v1.w);
      af[mb][st] = h;
    }
  }

  float m1f[4][4], m2f[4][4]; int i1[4][4];
  #pragma unroll
  for (int mb=0;mb<4;++mb)
    #pragma unroll
    for (int r=0;r<4;++r) { m1f[mb][r]=3.0e38f; m2f[mb][r]=3.0e38f; i1[mb][r]=0; }

  for (int cc = 0; cc < 64; ++cc) {
    const int cur = cc & 1;
    __syncthreads();                       // drains staging of chunk cc
    if (cc + 1 < 64) {                     // issue chunk cc+1 into other buffer
      const char* g = (const char*)(EhP + (size_t)(qtr*64 + cc + 1)*8192);
      #pragma unroll
      for (int r = 0; r < 4; ++r)
        gl_lds16(g + r*4096 + stag, (char*)&Bsh[cur^1][0] + r*4096 + stag);
    }

    f32x4 acc[4][2];
    #pragma unroll
    for (int mb=0;mb<4;++mb)
      #pragma unroll
      for (int nb=0;nb<2;++nb) { f32x4 z = {0.f,0.f,0.f,0.f}; acc[mb][nb] = z; }

    #pragma unroll
    for (int st = 0; st < 8; ++st) {
      half8 bf[2];
      bf[0] = *(const half8*)(&Bsh[cur][(st*2+0)*512 + lane*8]);
      bf[1] = *(const half8*)(&Bsh[cur][(st*2+1)*512 + lane*8]);
      #pragma unroll
      for (int nb = 0; nb < 2; ++nb)
        #pragma unroll
        for (int mb = 0; mb < 4; ++mb)
          acc[mb][nb] = __builtin_amdgcn_mfma_f32_16x16x32_f16(af[mb][st], bf[nb], acc[mb][nb], 0, 0, 0);
    }

    const int c = qtr*64 + cc;
    #pragma unroll
    for (int nb = 0; nb < 2; ++nb) {
      const int col = c*32 + nb*16 + lp;
      const float e2v = e2p[col];
      #pragma unroll
      for (int mb = 0; mb < 4; ++mb)
        #pragma unroll
        for (int r = 0; r < 4; ++r) {
          float s = fmaf(-2.0f, acc[mb][nb][r], e2v);
          m2f[mb][r] = __builtin_amdgcn_fmed3f(m1f[mb][r], m2f[mb][r], s);
          bool lt = s < m1f[mb][r];
          m1f[mb][r] = lt ? s : m1f[mb][r];
          i1[mb][r]  = lt ? col : i1[mb][r];
        }
    }
  }

  // merge across the 16 lp-lanes of each quad (waves own disjoint rows)
  #pragma unroll
  for (int off = 1; off <= 8; off <<= 1) {
    #pragma unroll
    for (int mb=0;mb<4;++mb)
      #pragma unroll
      for (int r=0;r<4;++r) {
        float o1 = __shfl_xor(m1f[mb][r], off);
        int   oi = __shfl_xor(i1[mb][r],  off);
        float o2 = __shfl_xor(m2f[mb][r], off);
        float hi = fmaxf(m1f[mb][r], o1);
        m2f[mb][r] = fminf(fminf(m2f[mb][r], o2), hi);
        if (o1 < m1f[mb][r]) { m1f[mb][r] = o1; i1[mb][r] = oi; }
      }
  }
  if (lp == 0) {
    #pragma unroll
    for (int mb=0;mb<4;++mb)
      #pragma unroll
      for (int r=0;r<4;++r) {
        int row = rowbase + mb*16 + q*4 + r;
        unsigned u = (__float_as_uint(m1f[mb][r]) & 0xFFFFE000u) | (unsigned)i1[mb][r];
        m1q[qtr*NPTS + row] = u;
        m2q[qtr*NPTS + row] = m2f[mb][r];
      }
  }
}

// ------------------------------------- merge 4 quarters, write idx/m1s, flag
__global__ void k_merge(const unsigned* __restrict__ m1q, const float* __restrict__ m2q,
                        int* __restrict__ idx, float* __restrict__ m1s,
                        int* __restrict__ flaglist, int* __restrict__ flagcount)
{
  const int row = blockIdx.x*256 + threadIdx.x;   // 128 blocks
  unsigned u0 = m1q[row], u1 = m1q[NPTS + row], u2 = m1q[2*NPTS + row], u3 = m1q[3*NPTS + row];
  float    w0 = m2q[row], w1 = m2q[NPTS + row], w2 = m2q[2*NPTS + row], w3 = m2q[3*NPTS + row];
  unsigned a = umin_(u0,u1), b = umax_(u0,u1), cx = umin_(u2,u3), d = umax_(u2,u3);
  unsigned m1g = umin_(a, cx);
  unsigned sec = umin_(umax_(a, cx), umin_(b, d));
  float m1f = __uint_as_float(m1g & 0xFFFFE000u);
  float secf = __uint_as_float(sec & 0xFFFFE000u);
  float m2g = fminf(fminf(fminf(w0,w1), fminf(w2,w3)), secf);
  idx[row] = (int)(m1g & 0x1FFFu);
  m1s[row] = m1f;
  if (m2g - m1f < WINDOW) {
    int p = atomicAdd(flagcount, 1);
    if (p < FLAGCAP) flaglist[p] = row;
  }
}

// -------------------------------- P2: rescan flagged rows, collect candidates
// grid 512 = 16 batch-slots x 32 K-slices (8 chunks each), dbuf LDS staging.
__launch_bounds__(256, 2)
__global__ void k_rescan(const float* __restrict__ X, const _Float16* __restrict__ EhP,
                         const float* __restrict__ e2p, const float* __restrict__ m1s,
                         const int* __restrict__ flaglist, const int* __restrict__ flagcount,
                         int* __restrict__ ccounts, int* __restrict__ candbuf)
{
  __shared__ __align__(16) _Float16 Bsh[2][8192];
  const int tid = threadIdx.x, lane = tid & 63, wid = tid >> 6;
  const int q = lane >> 4, lp = lane & 15;
  const int slice = blockIdx.x & 31, bslot = blockIdx.x >> 5;
  const int stag = wid*1024 + lane*16;
  int cnt = *flagcount; if (cnt > FLAGCAP) cnt = FLAGCAP;

  for (int batch = bslot; batch*256 < cnt; batch += 16) {
    const int base = batch*256 + wid*64;
    { // issue chunk slice*8 staging (overlaps A build)
      const char* g = (const char*)(EhP + (size_t)(slice*8)*8192);
      #pragma unroll
      for (int r = 0; r < 4; ++r)
        gl_lds16(g + r*4096 + stag, (char*)&Bsh[0][0] + r*4096 + stag);
    }
    int ga[4];
    #pragma unroll
    for (int mb=0;mb<4;++mb) {
      int fi = base + mb*16 + lp;
      ga[mb] = (fi < cnt) ? flaglist[fi] : 0;
    }
    float thr[4][4]; int fis[4][4];
    #pragma unroll
    for (int mb=0;mb<4;++mb)
      #pragma unroll
      for (int r=0;r<4;++r) {
        int fi = base + mb*16 + q*4 + r;
        fis[mb][r] = fi;
        if (fi < cnt) thr[mb][r] = m1s[flaglist[fi]] + WINDOW;
        else          thr[mb][r] = -3.0e38f;
      }
    half8 af[4][8];
    #pragma unroll
    for (int mb = 0; mb < 4; ++mb) {
      const float* xr = X + (size_t)ga[mb]*DDIM;
      #pragma unroll
      for (int st = 0; st < 8; ++st) {
        const float* p = xr + st*32 + q*8;
        float4 v0 = *(const float4*)p;
        float4 v1 = *(const float4*)(p + 4);
        half8 h;
        h[0]=(_Float16)(16.f*v0.x); h[1]=(_Float16)(16.f*v0.y);
        h[2]=(_Float16)(16.f*v0.z); h[3]=(_Float16)(16.f*v0.w);
        h[4]=(_Float16)(16.f*v1.x); h[5]=(_Float16)(16.f*v1.y);
        h[6]=(_Float16)(16.f*v1.z); h[7]=(_Float16)(16.f*v1.w);
        af[mb][st] = h;
      }
    }
    for (int j = 0; j < 8; ++j) {
      const int cur = j & 1;
      __syncthreads();
      if (j + 1 < 8) {
        const char* g = (const char*)(EhP + (size_t)(slice*8 + j + 1)*8192);
        #pragma unroll
        for (int r = 0; r < 4; ++r)
          gl_lds16(g + r*4096 + stag, (char*)&Bsh[cur^1][0] + r*4096 + stag);
      }
      f32x4 acc[4][2];
      #pragma unroll
      for (int mb=0;mb<4;++mb)
        #pragma unroll
        for (int nb=0;nb<2;++nb) { f32x4 z = {0.f,0.f,0.f,0.f}; acc[mb][nb] = z; }
      #pragma unroll
      for (int st = 0; st < 8; ++st) {
        half8 bf[2];
        bf[0] = *(const half8*)(&Bsh[cur][(st*2+0)*512 + lane*8]);
        bf[1] = *(const half8*)(&Bsh[cur][(st*2+1)*512 + lane*8]);
        #pragma unroll
        for (int nb = 0; nb < 2; ++nb)
          #pragma unroll
          for (int mb = 0; mb < 4; ++mb)
            acc[mb][nb] = __builtin_amdgcn_mfma_f32_16x16x32_f16(af[mb][st], bf[nb], acc[mb][nb], 0, 0, 0);
      }
      const int c = slice*8 + j;
      #pragma unroll
      for (int nb = 0; nb < 2; ++nb) {
        const int col = c*32 + nb*16 + lp;
        const float e2v = e2p[col];
        #pragma unroll
        for (int mb = 0; mb < 4; ++mb)
          #pragma unroll
          for (int r = 0; r < 4; ++r) {
            float s = fmaf(-2.0f, acc[mb][nb][r], e2v);
            if (s < thr[mb][r]) {
              int fi = fis[mb][r];
              int slot = atomicAdd(&ccounts[fi], 1);
              if (slot < CANDCAP) candbuf[fi*CANDCAP + slot] = col;
            }
          }
      }
    }
    __syncthreads();   // protect Bsh before next batch's preload
  }
}

// -------------------------------------- P3: exact fp64 argmin over candidates
__global__ void k_exact(const float* __restrict__ X, const float* __restrict__ Et,
                        const int* __restrict__ flaglist, const int* __restrict__ flagcount,
                        const int* __restrict__ ccounts, const int* __restrict__ candbuf,
                        int* __restrict__ idx)
{
  int cnt = *flagcount; if (cnt > FLAGCAP) cnt = FLAGCAP;
  const int lane = threadIdx.x & 63;
  const int w = blockIdx.x*4 + (threadIdx.x >> 6);      // 256 blocks -> 1024 waves
  for (int i = w; i < cnt; i += 1024) {
    const int g = flaglist[i];
    const int cc = ccounts[i];
    double best = 1.0e300; int bestk = 0x7FFFFFFF;
    if (cc <= CANDCAP) {
      float4 xv = *(const float4*)(X + (size_t)g*DDIM + lane*4);
      for (int c = 0; c < cc; ++c) {
        int k = candbuf[i*CANDCAP + c];
        float4 ev = *(const float4*)(Et + (size_t)k*DDIM + lane*4);
        double d0 = (double)xv.x - (double)ev.x, d1 = (double)xv.y - (double)ev.y;
        double d2 = (double)xv.z - (double)ev.z, d3 = (double)xv.w - (double)ev.w;
        double s = d0*d0 + d1*d1 + d2*d2 + d3*d3;
        #pragma unroll
        for (int off = 1; off < 64; off <<= 1) s += __shfl_xor(s, off);
        if (s < best || (s == best && k < bestk)) { best = s; bestk = k; }
      }
    } else {  // candbuf overflow: full exact scan (statistically ~never)
      double bb = 1.0e300; int bk = 0x7FFFFFFF;
      for (int k = lane; k < KCOD; k += 64) {
        double s = 0.0;
        for (int d = 0; d < DDIM; ++d) {
          double df = (double)X[(size_t)g*DDIM + d] - (double)Et[(size_t)k*DDIM + d];
          s += df*df;
        }
        if (s < bb || (s == bb && k < bk)) { bb = s; bk = k; }
      }
      #pragma unroll
      for (int off = 1; off < 64; off <<= 1) {
        double ob = __shfl_xor(bb, off); int ok = __shfl_xor(bk, off);
        if (ob < bb || (ob == bb && ok < bk)) { bb = ob; bk = ok; }
      }
      best = bb; bestk = bk;
    }
    if (lane == 0 && bestk != 0x7FFFFFFF) idx[g] = bestk;
  }
}

// -------------------------------------------------- P4: gather output + loss
__global__ void k_gather(const float* __restrict__ X, const float* __restrict__ Et,
                         const int* __restrict__ idx, float* __restrict__ out)
{
  const int lane = threadIdx.x & 63, wid = threadIdx.x >> 6;
  float lsum = 0.0f;
  for (int i = 0; i < 16; ++i) {
    int n = blockIdx.x*64 + i*4 + wid;
    int k = idx[n];
    float4 xv = *(const float4*)(X  + (size_t)n*DDIM + lane*4);
    float4 ev = *(const float4*)(Et + (size_t)k*DDIM + lane*4);
    *(float4*)(out + (size_t)n*DDIM + lane*4) = ev;   // ST fwd value == quantized
    float d0 = ev.x-xv.x, d1 = ev.y-xv.y, d2 = ev.z-xv.z, d3 = ev.w-xv.w;
    lsum += d0*d0 + d1*d1 + d2*d2 + d3*d3;
  }
  #pragma unroll
  for (int off = 1; off < 64; off <<= 1) lsum += __shfl_xor(lsum, off);
  if (lane == 0) atomicAdd(out + (size_t)NELEM, lsum * (1.25f/8388608.0f));
}

// ================================ launch ======================================
extern "C" void kernel_launch(void* const* d_in, const int* in_sizes, int n_in,
                              void* d_out, int out_size, void* d_ws, size_t ws_size,
                              hipStream_t stream)
{
  const float* X = (const float*)d_in[0];   // [32768][256]
  const float* E = (const float*)d_in[1];   // [256][8192]
  float* out = (float*)d_out;               // [8388608 quantized][1 loss]
  char* ws = (char*)d_ws;

  float*     Et        = (float*)(ws);                               // 8 MB
  _Float16*  EhP       = (_Float16*)(ws + 8388608);                  // 4 MB
  float*     e2p       = (float*)(ws + 12582912);                    // 32 KB
  unsigned*  m1q       = (unsigned*)(ws + 12615680);                 // 512 KB
  float*     m2q       = (float*)(ws + 13139968);                    // 512 KB
  float*     m1s       = (float*)(ws + 13664256);                    // 128 KB
  int*       idx       = (int*)(ws + 13795328);                      // 128 KB
  int*       flaglist  = (int*)(ws + 13926400);                      // 64 KB
  int*       ccounts   = (int*)(ws + 13991936);                      // 64 KB
  int*       candbuf   = (int*)(ws + 14057472);                      // 1 MB
  int*       flagcount = (int*)(ws + 15106048);                      // 4 B
  if (ws_size < (size_t)15106052) return;

  dim3 B(256);
  k_prepE <<<dim3(512),  B, 0, stream>>>(E, EhP, Et);
  k_e2z   <<<dim3(2048), B, 0, stream>>>(Et, e2p, ccounts, flagcount, out + NELEM);
  k_screen<<<dim3(512),  B, 0, stream>>>(X, EhP, e2p, m1q, m2q);
  k_merge <<<dim3(128),  B, 0, stream>>>(m1q, m2q, idx, m1s, flaglist, flagcount);
  k_rescan<<<dim3(512),  B, 0, stream>>>(X, EhP, e2p, m1s, flaglist, flagcount, ccounts, candbuf);
  k_exact <<<dim3(256),  B, 0, stream>>>(X, Et, flaglist, flagcount, ccounts, candbuf, idx);
  k_gather<<<dim3(512),  B, 0, stream>>>(X, Et, idx, out);
}